// Round 11
// baseline (473.127 us; speedup 1.0000x reference)
//
#include <hip/hip_runtime.h>

#define NN 100000
#define NE 1000000
#define D 128
#define ALPHA 0.5f

// ---------------- workspace layout (bytes), all 16B-aligned ----------------
// z       [NN][256] f32 : 0           (102,400,000)
// W2_big  [256][128] f32: 102,400,000 (+131,072)
// bias    [128] f32     : 102,531,072 (+512)
// cnt     [NN] i32      : 102,531,584 (+400,000)
// start   [NN] i32      : 102,931,584 (+400,000)
// binCnt / binBase / binCursor: 103,331,584 (+2048 each)
// buf     [2*NE] i32    : 103,337,728 (+8,000,000)
// rec4    [2*NE] i32    : 111,337,728 (+8,000,000) => need 119,337,728
// (proven available: round-9 took the 119,731,328-byte path)
#define OFF_W2     102400000UL
#define OFF_BIAS   102531072UL
#define OFF_CNT    102531584UL
#define OFF_START  102931584UL
#define OFF_BINC   103331584UL
#define OFF_BINB   103333632UL
#define OFF_BINCUR 103335680UL
#define OFF_BUF    103337728UL
#define OFF_REC    111337728UL

#define NB  391      // bins of 256 nodes
#define EPB 2048     // edges per block in count/place

// ---------------------------------------------------------------------------
// K0: fused weight W2_big[k][j] (256 x 128) for out = z @ W2_big + bias:
//   k<128 : ALPHA     * Wsd[j][k]        (z half 0 = agg of x[src] into dst)
//   k>=128: (1-ALPHA) * Wds[j][k-128]    (z half 1 = agg of x[dst] into src)
// bias[j] = ALPHA*bsd[j] + (1-ALPHA)*bds[j]
// ---------------------------------------------------------------------------
__global__ __launch_bounds__(256) void build_w2b(const float* __restrict__ Wsd,
                                                 const float* __restrict__ Wds,
                                                 const float* __restrict__ bsd,
                                                 const float* __restrict__ bds,
                                                 float* __restrict__ W2,
                                                 float* __restrict__ bias) {
    int idx = blockIdx.x * 256 + threadIdx.x;   // 0..32767
    int k = idx >> 7;
    int j = idx & 127;
    float v;
    if (k < 128) v = ALPHA * Wsd[j * D + k];
    else         v = (1.0f - ALPHA) * Wds[j * D + (k - 128)];
    W2[idx] = v;
    if (idx < 128) bias[idx] = ALPHA * bsd[idx] + (1.0f - ALPHA) * bds[idx];
}

// ---------------------------------------------------------------------------
// CSR build via two-level counting sort (verified r9). Record (4B):
//   rec = (keyLocal<<18) | (partner<<1) | half,  keyLocal = key & 255
// buf entry for gather = (partner<<1) | half  (= rec & 0x3FFFF).
// ---------------------------------------------------------------------------
__global__ __launch_bounds__(512) void zero_bins(int* __restrict__ binCnt) {
    int i = threadIdx.x;
    if (i < NB) binCnt[i] = 0;
}

__global__ __launch_bounds__(256) void count_bins(const int* __restrict__ esrc,
                                                  const int* __restrict__ edst,
                                                  int* __restrict__ binCnt) {
    __shared__ int h[NB];
    int t = threadIdx.x;
    for (int i = t; i < NB; i += 256) h[i] = 0;
    __syncthreads();
    int e0 = blockIdx.x * EPB;
    for (int i = t; i < EPB; i += 256) {
        int e = e0 + i;
        if (e < NE) {
            atomicAdd(&h[edst[e] >> 8], 1);
            atomicAdd(&h[esrc[e] >> 8], 1);
        }
    }
    __syncthreads();
    for (int i = t; i < NB; i += 256)
        if (h[i]) atomicAdd(&binCnt[i], h[i]);
}

__global__ __launch_bounds__(256) void scan_bins(const int* __restrict__ binCnt,
                                                 int* __restrict__ binBase,
                                                 int* __restrict__ binCursor) {
    __shared__ int v[NB];
    int t = threadIdx.x;
    for (int i = t; i < NB; i += 256) v[i] = binCnt[i];
    __syncthreads();
    if (t == 0) {
        int acc = 0;
        for (int i = 0; i < NB; ++i) { int c = v[i]; v[i] = acc; acc += c; }
    }
    __syncthreads();
    for (int i = t; i < NB; i += 256) { binBase[i] = v[i]; binCursor[i] = v[i]; }
}

__global__ __launch_bounds__(256) void place_bins(const int* __restrict__ esrc,
                                                  const int* __restrict__ edst,
                                                  int* __restrict__ binCursor,
                                                  int* __restrict__ rec4) {
    __shared__ int h[NB];
    __shared__ int base[NB];
    __shared__ int lcur[NB];
    int t = threadIdx.x;
    for (int i = t; i < NB; i += 256) h[i] = 0;
    __syncthreads();
    int e0 = blockIdx.x * EPB;
    for (int i = t; i < EPB; i += 256) {
        int e = e0 + i;
        if (e < NE) {
            atomicAdd(&h[edst[e] >> 8], 1);
            atomicAdd(&h[esrc[e] >> 8], 1);
        }
    }
    __syncthreads();
    for (int i = t; i < NB; i += 256) {
        if (h[i]) base[i] = atomicAdd(&binCursor[i], h[i]);
        lcur[i] = 0;
    }
    __syncthreads();
    for (int i = t; i < EPB; i += 256) {
        int e = e0 + i;
        if (e < NE) {
            int s = esrc[e], d = edst[e];
            int bd = d >> 8, bs = s >> 8;
            int p1 = atomicAdd(&lcur[bd], 1);
            rec4[base[bd] + p1] = ((d & 255) << 18) | (s << 1);
            int p2 = atomicAdd(&lcur[bs], 1);
            rec4[base[bs] + p2] = ((s & 255) << 18) | (d << 1) | 1;
        }
    }
}

__global__ __launch_bounds__(256) void build_csr(const int* __restrict__ rec4,
                                                 const int* __restrict__ binBase,
                                                 const int* __restrict__ binCnt,
                                                 int* __restrict__ buf,
                                                 int* __restrict__ start,
                                                 int* __restrict__ cnt_out) {
    __shared__ int hc[256];
    __shared__ int st[256];
    int b = blockIdx.x;
    int t = threadIdx.x;
    int node0 = b << 8;
    int r0 = binBase[b];
    int rn = binCnt[b];

    hc[t] = 0;
    __syncthreads();
    for (int i = t; i < rn; i += 256)
        atomicAdd(&hc[rec4[r0 + i] >> 18], 1);
    __syncthreads();
    if (t == 0) {
        int acc = 0;
        for (int i = 0; i < 256; ++i) { st[i] = acc; acc += hc[i]; }
    }
    __syncthreads();
    int n = node0 + t;
    if (n < NN) {
        start[n]   = r0 + st[t];
        cnt_out[n] = hc[t];
    }
    hc[t] = st[t];          // reuse as local cursor
    __syncthreads();
    for (int i = t; i < rn; i += 256) {
        int r = rec4[r0 + i];
        int pos = atomicAdd(&hc[r >> 18], 1);
        buf[r0 + pos] = r & 0x3FFFF;    // (partner<<1) | half
    }
}

// ---------------------------------------------------------------------------
// K3: gather_z. One wave per node; lane = dims {2l, 2l+1}.
//   z[n][0:128]   = sum over half0 entries of x[partner]
//   z[n][128:256] = sum over half1 entries of x[partner]
// x is 51.2 MB -> L3-resident; half-tag branch is wave-uniform (no divergence).
// ---------------------------------------------------------------------------
__global__ __launch_bounds__(256) void gather_z(const int* __restrict__ start,
                                                const int* __restrict__ cnt,
                                                const int* __restrict__ buf,
                                                const float* __restrict__ x,
                                                float* __restrict__ z) {
    int wave = blockIdx.x * 4 + (threadIdx.x >> 6);
    int lane = threadIdx.x & 63;
    if (wave >= NN) return;
    const int s0 = start[wave];
    const int e0 = s0 + cnt[wave];
    const int l2 = lane << 1;

    float a0 = 0.f, a1 = 0.f;   // half 0
    float b0 = 0.f, b1 = 0.f;   // half 1

#define ACCUM(v, p) if ((v) & 1) { b0 += (p).x; b1 += (p).y; } \
                    else         { a0 += (p).x; a1 += (p).y; }

    int i = s0;
    for (; i + 4 <= e0; i += 4) {
        int v0 = buf[i], v1 = buf[i + 1], v2 = buf[i + 2], v3 = buf[i + 3];
        float2 p0 = *(const float2*)&x[(size_t)(v0 >> 1) * D + l2];
        float2 p1 = *(const float2*)&x[(size_t)(v1 >> 1) * D + l2];
        float2 p2 = *(const float2*)&x[(size_t)(v2 >> 1) * D + l2];
        float2 p3 = *(const float2*)&x[(size_t)(v3 >> 1) * D + l2];
        ACCUM(v0, p0) ACCUM(v1, p1) ACCUM(v2, p2) ACCUM(v3, p3)
    }
    for (; i < e0; ++i) {
        int v0 = buf[i];
        float2 p0 = *(const float2*)&x[(size_t)(v0 >> 1) * D + l2];
        ACCUM(v0, p0)
    }
#undef ACCUM

    *(float2*)&z[(size_t)wave * 256 + l2]       = make_float2(a0, a1);
    *(float2*)&z[(size_t)wave * 256 + 128 + l2] = make_float2(b0, b1);
}

// ---------------------------------------------------------------------------
// K4: transform_z GEMM  out[NN][128] = z[NN][256] @ W2_big[256][128] + bias
// 64 rows x 128 cols per 256-thread block; 4 rows x (2 groups of 4 cols) per
// thread; K=256. No LDS, no syncs: A-reads are 4-address wave broadcasts,
// B-reads contiguous 64-float spans (W2_big is 128 KB, L2-resident).
// ---------------------------------------------------------------------------
__global__ __launch_bounds__(256) void transform_z(const float* __restrict__ z,
                                                   const float* __restrict__ W2,
                                                   const float* __restrict__ bias,
                                                   float* __restrict__ out) {
    const int tid  = threadIdx.x;
    const int brow = blockIdx.x * 64;
    const int ty   = tid >> 4;          // 0..15 -> rows ty*4..ty*4+3
    const int tx   = tid & 15;
    const int c0   = tx << 2;           // col groups c0 and 64+c0

    float acc[4][2][4];
#pragma unroll
    for (int i = 0; i < 4; ++i)
#pragma unroll
        for (int g = 0; g < 2; ++g)
#pragma unroll
            for (int c = 0; c < 4; ++c) acc[i][g][c] = 0.f;

    size_t zbase[4];
    int    rvalid[4];
#pragma unroll
    for (int i = 0; i < 4; ++i) {
        int row = brow + ty * 4 + i;
        rvalid[i] = (row < NN);
        zbase[i]  = (size_t)(rvalid[i] ? row : 0) * 256;
    }

#pragma unroll 2
    for (int k0 = 0; k0 < 256; k0 += 4) {
        float4 av[4];
#pragma unroll
        for (int i = 0; i < 4; ++i)
            av[i] = *(const float4*)&z[zbase[i] + k0];
#pragma unroll
        for (int j = 0; j < 4; ++j) {
            float4 q0 = *(const float4*)&W2[(k0 + j) * 128 + c0];
            float4 q1 = *(const float4*)&W2[(k0 + j) * 128 + 64 + c0];
#pragma unroll
            for (int i = 0; i < 4; ++i) {
                float a = (&av[i].x)[j];
                acc[i][0][0] += a * q0.x; acc[i][0][1] += a * q0.y;
                acc[i][0][2] += a * q0.z; acc[i][0][3] += a * q0.w;
                acc[i][1][0] += a * q1.x; acc[i][1][1] += a * q1.y;
                acc[i][1][2] += a * q1.z; acc[i][1][3] += a * q1.w;
            }
        }
    }

    float4 bb0 = *(const float4*)&bias[c0];
    float4 bb1 = *(const float4*)&bias[64 + c0];
#pragma unroll
    for (int i = 0; i < 4; ++i) {
        if (!rvalid[i]) continue;
        int row = brow + ty * 4 + i;
        float4 o0 = make_float4(acc[i][0][0] + bb0.x, acc[i][0][1] + bb0.y,
                                acc[i][0][2] + bb0.z, acc[i][0][3] + bb0.w);
        float4 o1 = make_float4(acc[i][1][0] + bb1.x, acc[i][1][1] + bb1.y,
                                acc[i][1][2] + bb1.z, acc[i][1][3] + bb1.w);
        *(float4*)&out[(size_t)row * D + c0]      = o0;
        *(float4*)&out[(size_t)row * D + 64 + c0] = o1;
    }
}

// ---------------------------------------------------------------------------
extern "C" void kernel_launch(void* const* d_in, const int* in_sizes, int n_in,
                              void* d_out, int out_size, void* d_ws, size_t ws_size,
                              hipStream_t stream) {
    const float* x    = (const float*)d_in[0];
    const int*   esrc = (const int*)  d_in[1];
    const int*   edst = (const int*)  d_in[2];
    const float* Wsd  = (const float*)d_in[3];
    const float* bsd  = (const float*)d_in[4];
    const float* Wds  = (const float*)d_in[5];
    const float* bds  = (const float*)d_in[6];
    float* out = (float*)d_out;

    char*  ws       = (char*)d_ws;
    float* z        = (float*)ws;
    float* W2       = (float*)(ws + OFF_W2);
    float* bias     = (float*)(ws + OFF_BIAS);
    int*   cnt      = (int*)(ws + OFF_CNT);
    int*   start    = (int*)(ws + OFF_START);
    int*   binCnt   = (int*)(ws + OFF_BINC);
    int*   binBase  = (int*)(ws + OFF_BINB);
    int*   binCursor= (int*)(ws + OFF_BINCUR);
    int*   buf      = (int*)(ws + OFF_BUF);
    int*   rec4     = (int*)(ws + OFF_REC);

    const int nblk = (NE + EPB - 1) / EPB;   // 489

    build_w2b<<<128, 256, 0, stream>>>(Wsd, Wds, bsd, bds, W2, bias);
    zero_bins<<<1, 512, 0, stream>>>(binCnt);
    count_bins<<<nblk, 256, 0, stream>>>(esrc, edst, binCnt);
    scan_bins<<<1, 256, 0, stream>>>(binCnt, binBase, binCursor);
    place_bins<<<nblk, 256, 0, stream>>>(esrc, edst, binCursor, rec4);
    build_csr<<<NB, 256, 0, stream>>>(rec4, binBase, binCnt, buf, start, cnt);
    gather_z<<<(NN + 3) / 4, 256, 0, stream>>>(start, cnt, buf, x, z);
    transform_z<<<(NN + 63) / 64, 256, 0, stream>>>(z, W2, bias, out);
}

// Round 12
// 428.308 us; speedup vs baseline: 1.1046x; 1.1046x over previous
//
#include <hip/hip_runtime.h>

#define NN 100000
#define NE 1000000
#define D 128
#define ALPHA 0.5f

// ---------------- workspace layout (bytes), all 16B-aligned ----------------
// z       [NN][256] f32 : 0           (102,400,000)
// W2_big  [256][128] f32: 102,400,000 (+131,072)
// bias    [128] f32     : 102,531,072 (+512)
// cnt     [NN] i32      : 102,531,584 (+400,000)
// start   [NN] i32      : 102,931,584 (+400,000)
// binCnt / binBase / binCursor: 103,331,584 (+2048 each)
// buf     [2*NE] i32    : 103,337,728 (+8,000,000)
// rec4    [2*NE] i32    : 111,337,728 (+8,000,000) => need 119,337,728
// (proven: r9 ran the 119,731,328-byte layout)
#define OFF_W2     102400000UL
#define OFF_BIAS   102531072UL
#define OFF_CNT    102531584UL
#define OFF_START  102931584UL
#define OFF_BINC   103331584UL
#define OFF_BINB   103333632UL
#define OFF_BINCUR 103335680UL
#define OFF_BUF    103337728UL
#define OFF_REC    111337728UL

#define NB  391      // bins of 256 nodes
#define EPB 2048     // edges per block in count/place

// ---------------------------------------------------------------------------
// K0: fused weight W2_big[k][j] (256 x 128) for out = z @ W2_big + bias:
//   k<128 : ALPHA     * Wsd[j][k]        (z half 0 = agg of x[src] into dst)
//   k>=128: (1-ALPHA) * Wds[j][k-128]    (z half 1 = agg of x[dst] into src)
// bias[j] = ALPHA*bsd[j] + (1-ALPHA)*bds[j]
// ---------------------------------------------------------------------------
__global__ __launch_bounds__(256) void build_w2b(const float* __restrict__ Wsd,
                                                 const float* __restrict__ Wds,
                                                 const float* __restrict__ bsd,
                                                 const float* __restrict__ bds,
                                                 float* __restrict__ W2,
                                                 float* __restrict__ bias) {
    int idx = blockIdx.x * 256 + threadIdx.x;   // 0..32767
    int k = idx >> 7;
    int j = idx & 127;
    float v;
    if (k < 128) v = ALPHA * Wsd[j * D + k];
    else         v = (1.0f - ALPHA) * Wds[j * D + (k - 128)];
    W2[idx] = v;
    if (idx < 128) bias[idx] = ALPHA * bsd[idx] + (1.0f - ALPHA) * bds[idx];
}

// ---------------------------------------------------------------------------
// CSR build via two-level counting sort (verified r9). Record (4B):
//   rec = (keyLocal<<18) | (partner<<1) | half,  keyLocal = key & 255
// buf entry for gather = (partner<<1) | half  (= rec & 0x3FFFF).
// ---------------------------------------------------------------------------
__global__ __launch_bounds__(512) void zero_bins(int* __restrict__ binCnt) {
    int i = threadIdx.x;
    if (i < NB) binCnt[i] = 0;
}

__global__ __launch_bounds__(256) void count_bins(const int* __restrict__ esrc,
                                                  const int* __restrict__ edst,
                                                  int* __restrict__ binCnt) {
    __shared__ int h[NB];
    int t = threadIdx.x;
    for (int i = t; i < NB; i += 256) h[i] = 0;
    __syncthreads();
    int e0 = blockIdx.x * EPB;
    for (int i = t; i < EPB; i += 256) {
        int e = e0 + i;
        if (e < NE) {
            atomicAdd(&h[edst[e] >> 8], 1);
            atomicAdd(&h[esrc[e] >> 8], 1);
        }
    }
    __syncthreads();
    for (int i = t; i < NB; i += 256)
        if (h[i]) atomicAdd(&binCnt[i], h[i]);
}

__global__ __launch_bounds__(256) void scan_bins(const int* __restrict__ binCnt,
                                                 int* __restrict__ binBase,
                                                 int* __restrict__ binCursor) {
    __shared__ int v[NB];
    int t = threadIdx.x;
    for (int i = t; i < NB; i += 256) v[i] = binCnt[i];
    __syncthreads();
    if (t == 0) {
        int acc = 0;
        for (int i = 0; i < NB; ++i) { int c = v[i]; v[i] = acc; acc += c; }
    }
    __syncthreads();
    for (int i = t; i < NB; i += 256) { binBase[i] = v[i]; binCursor[i] = v[i]; }
}

__global__ __launch_bounds__(256) void place_bins(const int* __restrict__ esrc,
                                                  const int* __restrict__ edst,
                                                  int* __restrict__ binCursor,
                                                  int* __restrict__ rec4) {
    __shared__ int h[NB];
    __shared__ int base[NB];
    __shared__ int lcur[NB];
    int t = threadIdx.x;
    for (int i = t; i < NB; i += 256) h[i] = 0;
    __syncthreads();
    int e0 = blockIdx.x * EPB;
    for (int i = t; i < EPB; i += 256) {
        int e = e0 + i;
        if (e < NE) {
            atomicAdd(&h[edst[e] >> 8], 1);
            atomicAdd(&h[esrc[e] >> 8], 1);
        }
    }
    __syncthreads();
    for (int i = t; i < NB; i += 256) {
        if (h[i]) base[i] = atomicAdd(&binCursor[i], h[i]);
        lcur[i] = 0;
    }
    __syncthreads();
    for (int i = t; i < EPB; i += 256) {
        int e = e0 + i;
        if (e < NE) {
            int s = esrc[e], d = edst[e];
            int bd = d >> 8, bs = s >> 8;
            int p1 = atomicAdd(&lcur[bd], 1);
            rec4[base[bd] + p1] = ((d & 255) << 18) | (s << 1);
            int p2 = atomicAdd(&lcur[bs], 1);
            rec4[base[bs] + p2] = ((s & 255) << 18) | (d << 1) | 1;
        }
    }
}

__global__ __launch_bounds__(256) void build_csr(const int* __restrict__ rec4,
                                                 const int* __restrict__ binBase,
                                                 const int* __restrict__ binCnt,
                                                 int* __restrict__ buf,
                                                 int* __restrict__ start,
                                                 int* __restrict__ cnt_out) {
    __shared__ int hc[256];
    __shared__ int st[256];
    int b = blockIdx.x;
    int t = threadIdx.x;
    int node0 = b << 8;
    int r0 = binBase[b];
    int rn = binCnt[b];

    hc[t] = 0;
    __syncthreads();
    for (int i = t; i < rn; i += 256)
        atomicAdd(&hc[rec4[r0 + i] >> 18], 1);
    __syncthreads();
    if (t == 0) {
        int acc = 0;
        for (int i = 0; i < 256; ++i) { st[i] = acc; acc += hc[i]; }
    }
    __syncthreads();
    int n = node0 + t;
    if (n < NN) {
        start[n]   = r0 + st[t];
        cnt_out[n] = hc[t];
    }
    hc[t] = st[t];          // reuse as local cursor
    __syncthreads();
    for (int i = t; i < rn; i += 256) {
        int r = rec4[r0 + i];
        int pos = atomicAdd(&hc[r >> 18], 1);
        buf[r0 + pos] = r & 0x3FFFF;    // (partner<<1) | half
    }
}

// ---------------------------------------------------------------------------
// K3: gather_z (verified r11). One wave per node; lane = dims {2l, 2l+1}.
//   z[n][0:128]   = sum over half0 entries of x[partner]
//   z[n][128:256] = sum over half1 entries of x[partner]
// ---------------------------------------------------------------------------
__global__ __launch_bounds__(256) void gather_z(const int* __restrict__ start,
                                                const int* __restrict__ cnt,
                                                const int* __restrict__ buf,
                                                const float* __restrict__ x,
                                                float* __restrict__ z) {
    int wave = blockIdx.x * 4 + (threadIdx.x >> 6);
    int lane = threadIdx.x & 63;
    if (wave >= NN) return;
    const int s0 = start[wave];
    const int e0 = s0 + cnt[wave];
    const int l2 = lane << 1;

    float a0 = 0.f, a1 = 0.f;   // half 0
    float b0 = 0.f, b1 = 0.f;   // half 1

#define ACCUM(v, p) if ((v) & 1) { b0 += (p).x; b1 += (p).y; } \
                    else         { a0 += (p).x; a1 += (p).y; }

    int i = s0;
    for (; i + 4 <= e0; i += 4) {
        int v0 = buf[i], v1 = buf[i + 1], v2 = buf[i + 2], v3 = buf[i + 3];
        float2 p0 = *(const float2*)&x[(size_t)(v0 >> 1) * D + l2];
        float2 p1 = *(const float2*)&x[(size_t)(v1 >> 1) * D + l2];
        float2 p2 = *(const float2*)&x[(size_t)(v2 >> 1) * D + l2];
        float2 p3 = *(const float2*)&x[(size_t)(v3 >> 1) * D + l2];
        ACCUM(v0, p0) ACCUM(v1, p1) ACCUM(v2, p2) ACCUM(v3, p3)
    }
    for (; i < e0; ++i) {
        int v0 = buf[i];
        float2 p0 = *(const float2*)&x[(size_t)(v0 >> 1) * D + l2];
        ACCUM(v0, p0)
    }
#undef ACCUM

    *(float2*)&z[(size_t)wave * 256 + l2]       = make_float2(a0, a1);
    *(float2*)&z[(size_t)wave * 256 + 128 + l2] = make_float2(b0, b1);
}

// ---------------------------------------------------------------------------
// K4: transform_z GEMM  out[NN][128] = z[NN][256] @ W2_big[256][128] + bias
// r5-proven structure: 64x64 tile / 256 threads, 4x4 per-thread register
// block, A-tile (z rows) staged in LDS [64][132] (33.8 KB, 4 blocks/CU),
// K=256 as two 128-deep LDS passes. B streamed from L2-resident W2 (128 KB).
// Replaces the r11 no-LDS version (181 us, VALUBusy 27% - latency-bound on
// per-k dependent L1 loads with no reuse stage).
// ---------------------------------------------------------------------------
__global__ __launch_bounds__(256) void transform_z(const float* __restrict__ z,
                                                   const float* __restrict__ W2,
                                                   const float* __restrict__ bias,
                                                   float* __restrict__ out) {
    __shared__ float As[64][132];   // 33792 B
    const int tid  = threadIdx.x;
    const int brow = blockIdx.x * 64;
    const int bcol = blockIdx.y * 64;    // 0 or 64
    const int ty   = tid >> 4;           // 0..15 -> rows ty*4..ty*4+3
    const int tx   = tid & 15;           // 0..15 -> cols tx*4..tx*4+3

    float acc[4][4];
#pragma unroll
    for (int i = 0; i < 4; ++i)
#pragma unroll
        for (int j = 0; j < 4; ++j) acc[i][j] = 0.f;

    for (int kp = 0; kp < 2; ++kp) {
        // Stage z[brow..brow+63][kp*128 .. kp*128+127] -> As, coalesced float4.
#pragma unroll
        for (int i = 0; i < 8; ++i) {
            int f   = tid + i * 256;        // float4 index 0..2047
            int row = f >> 5;               // 0..63
            int kc  = (f & 31) << 2;        // 0,4,...,124
            float4 g = make_float4(0.f, 0.f, 0.f, 0.f);
            int grow = brow + row;
            if (grow < NN) g = *(const float4*)&z[(size_t)grow * 256 + kp * 128 + kc];
            *(float4*)&As[row][kc] = g;
        }
        __syncthreads();

#pragma unroll 2
        for (int k0 = 0; k0 < 128; k0 += 4) {
            float av[4][4], bv[4][4];
#pragma unroll
            for (int i = 0; i < 4; ++i) {
                float4 t = *(const float4*)&As[ty * 4 + i][k0];
                av[i][0] = t.x; av[i][1] = t.y; av[i][2] = t.z; av[i][3] = t.w;
            }
#pragma unroll
            for (int j = 0; j < 4; ++j) {
                float4 t = *(const float4*)&W2[(size_t)(kp * 128 + k0 + j) * 128 + bcol + tx * 4];
                bv[j][0] = t.x; bv[j][1] = t.y; bv[j][2] = t.z; bv[j][3] = t.w;
            }
#pragma unroll
            for (int i = 0; i < 4; ++i)
#pragma unroll
                for (int c = 0; c < 4; ++c)
#pragma unroll
                    for (int kk = 0; kk < 4; ++kk)
                        acc[i][c] += av[i][kk] * bv[kk][c];
        }
        __syncthreads();   // As reused next pass
    }

    float4 bb = *(const float4*)&bias[bcol + tx * 4];
#pragma unroll
    for (int i = 0; i < 4; ++i) {
        int row = brow + ty * 4 + i;
        if (row < NN) {
            float4 v = make_float4(acc[i][0] + bb.x, acc[i][1] + bb.y,
                                   acc[i][2] + bb.z, acc[i][3] + bb.w);
            *(float4*)&out[(size_t)row * D + bcol + tx * 4] = v;
        }
    }
}

// ---------------------------------------------------------------------------
extern "C" void kernel_launch(void* const* d_in, const int* in_sizes, int n_in,
                              void* d_out, int out_size, void* d_ws, size_t ws_size,
                              hipStream_t stream) {
    const float* x    = (const float*)d_in[0];
    const int*   esrc = (const int*)  d_in[1];
    const int*   edst = (const int*)  d_in[2];
    const float* Wsd  = (const float*)d_in[3];
    const float* bsd  = (const float*)d_in[4];
    const float* Wds  = (const float*)d_in[5];
    const float* bds  = (const float*)d_in[6];
    float* out = (float*)d_out;

    char*  ws       = (char*)d_ws;
    float* z        = (float*)ws;
    float* W2       = (float*)(ws + OFF_W2);
    float* bias     = (float*)(ws + OFF_BIAS);
    int*   cnt      = (int*)(ws + OFF_CNT);
    int*   start    = (int*)(ws + OFF_START);
    int*   binCnt   = (int*)(ws + OFF_BINC);
    int*   binBase  = (int*)(ws + OFF_BINB);
    int*   binCursor= (int*)(ws + OFF_BINCUR);
    int*   buf      = (int*)(ws + OFF_BUF);
    int*   rec4     = (int*)(ws + OFF_REC);

    const int nblk = (NE + EPB - 1) / EPB;   // 489

    build_w2b<<<128, 256, 0, stream>>>(Wsd, Wds, bsd, bds, W2, bias);
    zero_bins<<<1, 512, 0, stream>>>(binCnt);
    count_bins<<<nblk, 256, 0, stream>>>(esrc, edst, binCnt);
    scan_bins<<<1, 256, 0, stream>>>(binCnt, binBase, binCursor);
    place_bins<<<nblk, 256, 0, stream>>>(esrc, edst, binCursor, rec4);
    build_csr<<<NB, 256, 0, stream>>>(rec4, binBase, binCnt, buf, start, cnt);
    gather_z<<<(NN + 3) / 4, 256, 0, stream>>>(start, cnt, buf, x, z);
    transform_z<<<dim3((NN + 63) / 64, 2), 256, 0, stream>>>(z, W2, bias, out);
}